// Round 3
// baseline (628.825 us; speedup 1.0000x reference)
//
#include <hip/hip_runtime.h>

// Problem constants from the reference
constexpr int B = 2, C = 2, D = 160, H = 192, W = 224;
constexpr int HW = H * W;          // 43008
constexpr int S  = D * HW;         // 6,881,280 voxels per batch per channel

// Tiling: each 256-thread block computes a 4(d) x 8(h) x 32(w) output brick.
constexpr int TD = 4, TH = 8, TW = 32;
constexpr int M  = 4;                              // staging margin (|flow|<=4 in-tile)
constexpr int RD = TD + 2 * M;                     // 12
constexpr int RH = TH + 2 * M;                     // 16
constexpr int RW = TW + 2 * M;                     // 40
constexpr int NCELL = RD * RH * RW;                // 7680 cells -> 60 KB as float2
constexpr int ND = D / TD, NH = H / TH, NW = W / TW;   // 40, 24, 7
constexpr int TILES_PER_B = ND * NH * NW;          // 6720

__global__ __launch_bounds__(256, 2) void warp3d_tile(
    const float* __restrict__ I,     // [B,C,D,H,W]
    const float* __restrict__ flow,  // [B,3,D,H,W]
    float* __restrict__ out)         // [B,C,D,H,W]
{
    __shared__ float2 tile[NCELL];   // channel-interleaved staged region, 60 KB

    int bid = blockIdx.x;
    int b   = bid / TILES_PER_B;
    int t   = bid - b * TILES_PER_B;
    int td  = t / (NH * NW);
    int r   = t - td * (NH * NW);
    int th  = r / NW;
    int tw  = r - th * NW;
    int d0 = td * TD, h0 = th * TH, w0 = tw * TW;

    const float* __restrict__ I0 = I + (long)b * 2 * S;   // channel 0 plane
    const float* __restrict__ I1 = I0 + S;                // channel 1 plane

    // ---- Stage the (12 x 16 x 40) region, edge-clamped, channels interleaved
    for (int c = threadIdx.x; c < NCELL; c += 256) {
        int rx = c % RW;
        int t2 = c / RW;
        int ry = t2 % RH;
        int rz = t2 / RH;
        int gz = min(max(d0 - M + rz, 0), D - 1);
        int gy = min(max(h0 - M + ry, 0), H - 1);
        int gx = min(max(w0 - M + rx, 0), W - 1);
        int gi = gz * HW + gy * W + gx;
        tile[c] = make_float2(I0[gi], I1[gi]);
    }
    __syncthreads();

    int lw = threadIdx.x & 31;       // 0..31 -> w within tile
    int lh = threadIdx.x >> 5;       // 0..7  -> h within tile
    int h = h0 + lh, w = w0 + lw;
    int base_s = h * W + w;

    // ---- Load flow for my 4 voxels up front (fully coalesced 128B runs)
    const float* __restrict__ fl = flow + (long)b * 3 * S;
    float fxr[TD], fyr[TD], fzr[TD];
#pragma unroll
    for (int dd = 0; dd < TD; ++dd) {
        int o = (d0 + dd) * HW + base_s;
        fxr[dd] = fl[o];
        fyr[dd] = fl[S + o];
        fzr[dd] = fl[2 * S + o];
    }

    float* __restrict__ ob = out + (long)b * 2 * S;

#pragma unroll
    for (int dd = 0; dd < TD; ++dd) {
        int d = d0 + dd;
        float X = fxr[dd] + (float)w;
        float Y = fyr[dd] + (float)h;
        float Z = fzr[dd] + (float)d;

        int x0 = (int)floorf(X);
        int y0 = (int)floorf(Y);
        int z0 = (int)floorf(Z);
        int x1 = min(max(x0 + 1, 0), W - 1);
        int y1 = min(max(y0 + 1, 0), H - 1);
        int z1 = min(max(z0 + 1, 0), D - 1);
        x0 = min(max(x0, 0), W - 1);
        y0 = min(max(y0, 0), H - 1);
        z0 = min(max(z0, 0), D - 1);

        // Weights use the CLAMPED upper corner (matches reference exactly)
        float dx = (float)x1 - X;
        float dy = (float)y1 - Y;
        float dz = (float)z1 - Z;
        float ex = 1.0f - dx, ey = 1.0f - dy, ez = 1.0f - dz;

        float wa = dz * dx * dy, wb = dz * dx * ey;
        float wc = dz * ex * dy, wdd = dz * ex * ey;
        float we = ez * dx * dy, wf = ez * dx * ey;
        float wgg = ez * ex * dy, wh = ez * ex * ey;

        // Region-local indices of the clamped corners
        int ix0 = x0 - (w0 - M), ix1 = x1 - (w0 - M);
        int iy0 = y0 - (h0 - M), iy1 = y1 - (h0 - M);
        int iz0 = z0 - (d0 - M), iz1 = z1 - (d0 - M);

        bool inr = ((unsigned)ix0 < (unsigned)RW) & ((unsigned)ix1 < (unsigned)RW)
                 & ((unsigned)iy0 < (unsigned)RH) & ((unsigned)iy1 < (unsigned)RH)
                 & ((unsigned)iz0 < (unsigned)RD) & ((unsigned)iz1 < (unsigned)RD);

        float2 va, vb, vc, vd, ve, vf, vg, vh;
        if (inr) {
            int za = iz0 * (RH * RW), zb = iz1 * (RH * RW);
            int ya = iy0 * RW,        yb = iy1 * RW;
            va = tile[za + ya + ix0];
            vb = tile[za + yb + ix0];
            vc = tile[za + ya + ix1];
            vd = tile[za + yb + ix1];
            ve = tile[zb + ya + ix0];
            vf = tile[zb + yb + ix0];
            vg = tile[zb + ya + ix1];
            vh = tile[zb + yb + ix1];
        } else {
            // Rare (|flow|>4): exact global gather
            int za = z0 * HW, zb = z1 * HW;
            int ya = y0 * W,  yb = y1 * W;
            va = make_float2(I0[za + ya + x0], I1[za + ya + x0]);
            vb = make_float2(I0[za + yb + x0], I1[za + yb + x0]);
            vc = make_float2(I0[za + ya + x1], I1[za + ya + x1]);
            vd = make_float2(I0[za + yb + x1], I1[za + yb + x1]);
            ve = make_float2(I0[zb + ya + x0], I1[zb + ya + x0]);
            vf = make_float2(I0[zb + yb + x0], I1[zb + yb + x0]);
            vg = make_float2(I0[zb + ya + x1], I1[zb + ya + x1]);
            vh = make_float2(I0[zb + yb + x1], I1[zb + yb + x1]);
        }

        float o0 = wa * va.x + wb * vb.x + wc * vc.x + wdd * vd.x
                 + we * ve.x + wf * vf.x + wgg * vg.x + wh * vh.x;
        float o1 = wa * va.y + wb * vb.y + wc * vc.y + wdd * vd.y
                 + we * ve.y + wf * vf.y + wgg * vg.y + wh * vh.y;

        int oo = d * HW + base_s;
        ob[oo]     = o0;   // channel 0
        ob[S + oo] = o1;   // channel 1
    }
}

extern "C" void kernel_launch(void* const* d_in, const int* in_sizes, int n_in,
                              void* d_out, int out_size, void* d_ws, size_t ws_size,
                              hipStream_t stream) {
    const float* I    = (const float*)d_in[0];
    const float* flow = (const float*)d_in[1];
    float* out = (float*)d_out;

    int grid = B * TILES_PER_B;   // 13440 workgroups
    warp3d_tile<<<grid, 256, 0, stream>>>(I, flow, out);
}